// Round 4
// baseline (360.337 us; speedup 1.0000x reference)
//
#include <hip/hip_runtime.h>
#include <hip/hip_bf16.h>
#include <cstdint>
#include <cstddef>

// WideLSTM: N=32 blocks, I=64, H=128, B=16, T=256.
// 64 WGs = 32 blocks x 2 batch-groups (8 batches each), 512 thr (8 waves).
// D[gate,batch] = W (A operand, persistent regs) x [x|h] (B operand, LDS).
// B cols 8-15 DUPLICATE cols 0-7 (same LDS addr -> broadcast): every gate
// value lands in two lanes; epilogue partitions by accumulator ROW (lanes
// col<8 take rows {0,1}, col>=8 rows {2,3}) so all 64 lanes do useful
// trans/update work with no cross-lane exchange. c register-resident,
// one lgkm-only barrier/step, split accumulators (3-deep mfma chains).

#define TSTEPS 256

typedef float  f32x4  __attribute__((ext_vector_type(4)));
typedef float  f32x2  __attribute__((ext_vector_type(2)));
typedef __bf16 bf16x8 __attribute__((ext_vector_type(8)));
typedef short  s16x8  __attribute__((ext_vector_type(8)));

union Frag { s16x8 s; bf16x8 b; };

#define KSIG -1.4426950408889634f   // -1/ln2 (sigmoid)
#define KTAN  2.8853900817779268f   //  2/ln2 (tanh)

__device__ __forceinline__ short f2bf(float f) {
  uint32_t u = __builtin_bit_cast(uint32_t, f);
  u += 0x7fffu + ((u >> 16) & 1u);
  return (short)(u >> 16);
}

// lgkm-only barrier: global loads/stores stay in flight across it
__device__ __forceinline__ void sync_lds() {
  asm volatile("s_waitcnt lgkmcnt(0)" ::: "memory");
  __builtin_amdgcn_s_barrier();
  asm volatile("" ::: "memory");
}

__device__ __forceinline__ float sig2(float z) {   // rcp(1 + exp2(z))
  return __builtin_amdgcn_rcpf(1.f + __builtin_amdgcn_exp2f(z));
}

__device__ __forceinline__ f32x4 mf(const Frag a, const Frag bb, f32x4 c) {
  return __builtin_amdgcn_mfma_f32_16x16x32_bf16(a.b, bb.b, c, 0, 0, 0);
}

__global__ __launch_bounds__(512, 2) void wide_lstm(
    const float* __restrict__ x,   const float* __restrict__ h0,
    const float* __restrict__ c0,  const float* __restrict__ wih,
    const float* __restrict__ whh, const float* __restrict__ bih,
    const float* __restrict__ bhh, float* __restrict__ out)
{
  const int n    = blockIdx.x & 31;
  const int bg   = blockIdx.x >> 5;      // batch group: batches [8bg, 8bg+8)
  const int tid  = threadIdx.x;
  const int w    = tid >> 6;             // wave 0..7: gates [16w,16w+16) per type
  const int lane = tid & 63;
  const int col  = lane & 15;
  const int quad = lane >> 4;
  const int c8   = col & 7;              // batch within group
  const int e    = col >> 3;             // row-half: 0 -> rows {0,1}, 1 -> {2,3}
  const int hq2  = 16 * w + quad * 4 + 2 * e;  // first of this lane's 2 h
  const int b    = 8 * bg + c8;          // global batch this lane updates

  // [0,1088): h rows (8 x stride 136 shorts); [1088,1664): x rows (8 x 72)
  __shared__ alignas(16) short sbuf[2][1664];

  // ---- weights -> persistent A-fragments (A rows m = gate-in-tile = col) ----
  Frag wfr[6][4];
#pragma unroll
  for (int j = 0; j < 4; ++j) {
    const int g = 128 * j + 16 * w + col;
#pragma unroll
    for (int s = 0; s < 6; ++s) {
      const int k0 = 32 * s + quad * 8;
      const float* p = (s < 2) ? (wih + (size_t)(n * 512 + g) * 64  + k0)
                               : (whh + (size_t)(n * 512 + g) * 128 + (k0 - 64));
      const f32x4 lo = *(const f32x4*)p;
      const f32x4 hi = *(const f32x4*)(p + 4);
      Frag f;
      f.s[0]=f2bf(lo[0]); f.s[1]=f2bf(lo[1]); f.s[2]=f2bf(lo[2]); f.s[3]=f2bf(lo[3]);
      f.s[4]=f2bf(hi[0]); f.s[5]=f2bf(hi[1]); f.s[6]=f2bf(hi[2]); f.s[7]=f2bf(hi[3]);
      wfr[s][j] = f;
    }
  }

  // ---- biases for this lane's 8 gates (rows hq2, hq2+1 of each type) ----
  float kb0[4], kb1[4];
#pragma unroll
  for (int j = 0; j < 4; ++j) {
    const int base = n * 512 + 128 * j + 16 * w + quad * 4 + 2 * e;
    const f32x2 b1 = *(const f32x2*)(bih + base);
    const f32x2 b2 = *(const f32x2*)(bhh + base);
    const float k  = (j == 2) ? KTAN : KSIG;
    kb0[j] = k * (b1[0] + b2[0]);
    kb1[j] = k * (b1[1] + b2[1]);
  }

  // ---- init h(0), x(0), c(0) ----
  {
    const int bi = tid >> 6, j0 = (tid & 63) * 2;
    const f32x2 hv = *(const f32x2*)(h0 + (size_t)(8 * bg + bi) * 4096 + n * 128 + j0);
    *(uint32_t*)&sbuf[0][bi * 136 + j0] =
        (uint32_t)(uint16_t)f2bf(hv[0]) | ((uint32_t)(uint16_t)f2bf(hv[1]) << 16);
  }
  const float* xp = x + (size_t)(8 * bg + w) * (TSTEPS * 2048) + n * 64 + lane;
  sbuf[0][1088 + w * 72 + lane] = f2bf(xp[0]);
  float cg0, cg1;
  {
    const f32x2 cv = *(const f32x2*)(c0 + (size_t)b * 4096 + n * 128 + hq2);
    cg0 = cv[0]; cg1 = cv[1];
  }
  __syncthreads();

  float xr = xp[2048];                 // x(1)
  const float* xnext = xp + 2 * 2048;  // cursor at x(2)

  const int xoff  = 1088 + c8 * 72 + quad * 8;   // x B-frag base (s=0,1)
  const int hoff  = c8 * 136 + quad * 8;         // h B-frag base (s=2..5)
  const int sxoff = 1088 + w * 72 + lane;        // x staging slot
  const int hwoff = c8 * 136 + hq2;              // h write slot
  float* outp = out + (size_t)b * (TSTEPS * 4096) + n * 128 + hq2;
  float ho0 = 0.f, ho1 = 0.f;

#define LSTM_STEP(CUR, NXT, S)                                               \
  {                                                                          \
    const short* sb = sbuf[CUR];                                             \
    Frag bf[6];                                                              \
    bf[0].s = *(const s16x8*)&sb[xoff];                                      \
    bf[1].s = *(const s16x8*)&sb[xoff + 32];                                 \
    bf[2].s = *(const s16x8*)&sb[hoff];                                      \
    bf[3].s = *(const s16x8*)&sb[hoff + 32];                                 \
    bf[4].s = *(const s16x8*)&sb[hoff + 64];                                 \
    bf[5].s = *(const s16x8*)&sb[hoff + 96];                                 \
    sbuf[NXT][sxoff] = f2bf(xr);                                             \
    if ((S) + 2 < TSTEPS) { xr = *xnext; xnext += 2048; }                    \
    f32x4 ac1[4], ac2[4];                                                    \
    _Pragma("unroll") for (int j = 0; j < 4; ++j) {                          \
      ac1[j] = (f32x4){0.f, 0.f, 0.f, 0.f};                                  \
      ac2[j] = (f32x4){0.f, 0.f, 0.f, 0.f};                                  \
    }                                                                        \
    _Pragma("unroll") for (int j = 0; j < 4; ++j) {                          \
      ac1[j] = mf(wfr[0][j], bf[0], ac1[j]);                                 \
      ac2[j] = mf(wfr[3][j], bf[3], ac2[j]);                                 \
    }                                                                        \
    _Pragma("unroll") for (int j = 0; j < 4; ++j) {                          \
      ac1[j] = mf(wfr[1][j], bf[1], ac1[j]);                                 \
      ac2[j] = mf(wfr[4][j], bf[4], ac2[j]);                                 \
    }                                                                        \
    _Pragma("unroll") for (int j = 0; j < 4; ++j) {                          \
      ac1[j] = mf(wfr[2][j], bf[2], ac1[j]);                                 \
      ac2[j] = mf(wfr[5][j], bf[5], ac2[j]);                                 \
    }                                                                        \
    float g0[4], g1[4];                                                      \
    _Pragma("unroll") for (int j = 0; j < 4; ++j) {                          \
      const float a0 = e ? ac1[j][2] : ac1[j][0];                            \
      const float a1 = e ? ac1[j][3] : ac1[j][1];                            \
      const float d0 = e ? ac2[j][2] : ac2[j][0];                            \
      const float d1 = e ? ac2[j][3] : ac2[j][1];                            \
      g0[j] = a0 + d0; g1[j] = a1 + d1;                                      \
    }                                                                        \
    const float si0 = sig2(__builtin_fmaf(g0[0], KSIG, kb0[0]));             \
    const float sf0 = sig2(__builtin_fmaf(g0[1], KSIG, kb0[1]));             \
    const float sg0 = sig2(__builtin_fmaf(g0[2], KTAN, kb0[2]));             \
    const float so0 = sig2(__builtin_fmaf(g0[3], KSIG, kb0[3]));             \
    const float si1 = sig2(__builtin_fmaf(g1[0], KSIG, kb1[0]));             \
    const float sf1 = sig2(__builtin_fmaf(g1[1], KSIG, kb1[1]));             \
    const float sg1 = sig2(__builtin_fmaf(g1[2], KTAN, kb1[2]));             \
    const float so1 = sig2(__builtin_fmaf(g1[3], KSIG, kb1[3]));             \
    float cn0 = __builtin_fmaf(sf0, cg0, si0);                               \
    cn0 = __builtin_fmaf(-2.f, si0 * sg0, cn0);                              \
    cg0 = cn0;                                                               \
    float cn1 = __builtin_fmaf(sf1, cg1, si1);                               \
    cn1 = __builtin_fmaf(-2.f, si1 * sg1, cn1);                              \
    cg1 = cn1;                                                               \
    ho0 = so0 * __builtin_fmaf(-2.f, sig2(KTAN * cn0), 1.f);                 \
    ho1 = so1 * __builtin_fmaf(-2.f, sig2(KTAN * cn1), 1.f);                 \
    *(uint32_t*)&sbuf[NXT][hwoff] =                                          \
        (uint32_t)(uint16_t)f2bf(ho0) | ((uint32_t)(uint16_t)f2bf(ho1) << 16); \
    f32x2 ov; ov[0] = ho0; ov[1] = ho1;                                      \
    *(f32x2*)outp = ov;                                                      \
    outp += 4096;                                                            \
    sync_lds();                                                              \
  }

  for (int t = 0; t < TSTEPS; t += 2) {
    LSTM_STEP(0, 1, t);
    LSTM_STEP(1, 0, t + 1);
  }
#undef LSTM_STEP

  // ---- h_n / c_n ----
  float* hn = out + 16777216 + (size_t)b * 4096 + n * 128 + hq2;
  f32x2 hv; hv[0] = ho0; hv[1] = ho1;
  f32x2 cv; cv[0] = cg0; cv[1] = cg1;
  *(f32x2*)hn = hv;
  *(f32x2*)(hn + 65536) = cv;
}

extern "C" void kernel_launch(void* const* d_in, const int* in_sizes, int n_in,
                              void* d_out, int out_size, void* d_ws, size_t ws_size,
                              hipStream_t stream) {
  const float* x   = (const float*)d_in[0];
  const float* h0  = (const float*)d_in[1];
  const float* c0  = (const float*)d_in[2];
  const float* wih = (const float*)d_in[3];
  const float* whh = (const float*)d_in[4];
  const float* bih = (const float*)d_in[5];
  const float* bhh = (const float*)d_in[6];
  float* out = (float*)d_out;
  wide_lstm<<<64, 512, 0, stream>>>(x, h0, c0, wih, whh, bih, bhh, out);
}

// Round 5
// 292.403 us; speedup vs baseline: 1.2323x; 1.2323x over previous
//
#include <hip/hip_runtime.h>
#include <hip/hip_bf16.h>
#include <cstdint>
#include <cstddef>

// WideLSTM: N=32 blocks, I=64, H=128, B=16, T=256.
// 128 WGs = 32 blocks x 4 batch-groups (4 batches each), 512 thr (8 waves).
// Model: step = mfma_phase (192 tiles x 4.85 cyc = 930, invariant) +
// valu_phase (scales 1/W) + overhead. W=128 gives perfect epilogue packing:
// B cols = 4 batches x 4 dups; lane (col=4*e2+b4) takes acc row r=e2 ->
// exactly ONE (batch,h) update per lane (10 trans-issues/wave).
// Bias rides in as MFMA C-operand (chain 1) + persistent zero-C (chain 2):
// no per-step acc init. One lgkm-only barrier/step; c register-resident.

#define TSTEPS 256

typedef float  f32x4  __attribute__((ext_vector_type(4)));
typedef float  f32x2  __attribute__((ext_vector_type(2)));
typedef __bf16 bf16x8 __attribute__((ext_vector_type(8)));
typedef short  s16x8  __attribute__((ext_vector_type(8)));

union Frag { s16x8 s; bf16x8 b; };

#define KSIG -1.4426950408889634f   // -1/ln2 (sigmoid)
#define KTAN  2.8853900817779268f   //  2/ln2 (tanh)

__device__ __forceinline__ short f2bf(float f) {
  uint32_t u = __builtin_bit_cast(uint32_t, f);
  u += 0x7fffu + ((u >> 16) & 1u);
  return (short)(u >> 16);
}

// lgkm-only barrier: global loads/stores stay in flight across it
__device__ __forceinline__ void sync_lds() {
  asm volatile("s_waitcnt lgkmcnt(0)" ::: "memory");
  __builtin_amdgcn_s_barrier();
  asm volatile("" ::: "memory");
}

__device__ __forceinline__ float sig2(float z) {   // rcp(1 + exp2(z))
  return __builtin_amdgcn_rcpf(1.f + __builtin_amdgcn_exp2f(z));
}

__device__ __forceinline__ f32x4 mf(const Frag a, const Frag bb, f32x4 c) {
  return __builtin_amdgcn_mfma_f32_16x16x32_bf16(a.b, bb.b, c, 0, 0, 0);
}

__global__ __launch_bounds__(512, 2) void wide_lstm(
    const float* __restrict__ x,   const float* __restrict__ h0,
    const float* __restrict__ c0,  const float* __restrict__ wih,
    const float* __restrict__ whh, const float* __restrict__ bih,
    const float* __restrict__ bhh, float* __restrict__ out)
{
  const int n    = blockIdx.x & 31;
  const int bg   = blockIdx.x >> 5;      // batch group: batches [4bg, 4bg+4)
  const int tid  = threadIdx.x;
  const int w    = tid >> 6;             // wave 0..7: h-tile [16w, 16w+16)
  const int lane = tid & 63;
  const int col  = lane & 15;
  const int quad = lane >> 4;
  const int b4   = col & 3;              // batch within group
  const int e2   = col >> 2;             // acc row r this lane keeps (0..3)
  const int hloc = 4 * quad + e2;        // h within wave's 16-tile
  const int hgl  = 16 * w + hloc;        // h within block (0..127)
  const int b    = 4 * bg + b4;          // global batch this lane updates

  // h: 4 rows x stride 144 shorts (bank-tuned: 8*b4+4*quad, <=2-way)
  __shared__ alignas(16) short hbuf[2][4 * 144];
  // x: 4 rows x stride 96 shorts (16*b4+16*s+4*quad, <=2-way)
  __shared__ alignas(16) short xbuf[2][4 * 96];

  // ---- weights -> persistent A-fragments ----
  // A tile j (gate type): lane holds W[g = 128j + 16w + col][k = 32s + quad*8 + jj]
  Frag wfr[6][4];
#pragma unroll
  for (int j = 0; j < 4; ++j) {
    const int g = 128 * j + 16 * w + col;
#pragma unroll
    for (int s = 0; s < 6; ++s) {
      const int k0 = 32 * s + quad * 8;
      const float* p = (s < 2) ? (wih + (size_t)(n * 512 + g) * 64  + k0)
                               : (whh + (size_t)(n * 512 + g) * 128 + (k0 - 64));
      const f32x4 lo = *(const f32x4*)p;
      const f32x4 hi = *(const f32x4*)(p + 4);
      Frag f;
      f.s[0]=f2bf(lo[0]); f.s[1]=f2bf(lo[1]); f.s[2]=f2bf(lo[2]); f.s[3]=f2bf(lo[3]);
      f.s[4]=f2bf(hi[0]); f.s[5]=f2bf(hi[1]); f.s[6]=f2bf(hi[2]); f.s[7]=f2bf(hi[3]);
      wfr[s][j] = f;
    }
  }

  // ---- bias in MFMA C-layout (row = quad*4+r, col-independent) ----
  f32x4 cb[4];
#pragma unroll
  for (int j = 0; j < 4; ++j) {
    const int base = n * 512 + 128 * j + 16 * w + quad * 4;
    const f32x4 b1 = *(const f32x4*)(bih + base);
    const f32x4 b2 = *(const f32x4*)(bhh + base);
#pragma unroll
    for (int r = 0; r < 4; ++r) cb[j][r] = b1[r] + b2[r];
  }
  const f32x4 kzero = (f32x4){0.f, 0.f, 0.f, 0.f};

  // ---- init h(0), x(0), c(0) ----
  if (tid < 256) {
    const int bi = tid >> 6, j2 = (tid & 63) * 2;
    const f32x2 hv = *(const f32x2*)(h0 + (size_t)(4 * bg + bi) * 4096 + n * 128 + j2);
    *(uint32_t*)&hbuf[0][bi * 144 + j2] =
        (uint32_t)(uint16_t)f2bf(hv[0]) | ((uint32_t)(uint16_t)f2bf(hv[1]) << 16);
  }
  const int bq = tid >> 6;               // staging batch (tid<256)
  const int kq = tid & 63;               // staging k
  const float* xp = x + (size_t)(4 * bg + bq) * (TSTEPS * 2048) + n * 64 + kq;
  float xr = 0.f;
  if (tid < 256) {
    xbuf[0][bq * 96 + kq] = f2bf(xp[0]);
    xr = xp[2048];                       // x(1)
  }
  const float* xnext = xp + 2 * 2048;    // cursor at x(2)
  float cg = c0[(size_t)b * 4096 + n * 128 + hgl];
  __syncthreads();

  const int xoff  = b4 * 96  + quad * 8;     // x B-frag base (s=0,1)
  const int hoff  = b4 * 144 + quad * 8;     // h B-frag base (s=2..5)
  const int sxoff = bq * 96 + kq;            // x staging slot (tid<256)
  const int hwoff = b4 * 144 + hgl;          // h write slot
  float* outp = out + (size_t)b * (TSTEPS * 4096) + n * 128 + hgl;
  float ho = 0.f;
  const bool m1 = (e2 & 1), m2 = (e2 & 2);

#define LSTM_STEP(CUR, NXT, S)                                               \
  {                                                                          \
    Frag bf[6];                                                              \
    bf[0].s = *(const s16x8*)&xbuf[CUR][xoff];                               \
    bf[1].s = *(const s16x8*)&xbuf[CUR][xoff + 32];                          \
    bf[2].s = *(const s16x8*)&hbuf[CUR][hoff];                               \
    bf[3].s = *(const s16x8*)&hbuf[CUR][hoff + 32];                          \
    bf[4].s = *(const s16x8*)&hbuf[CUR][hoff + 64];                          \
    bf[5].s = *(const s16x8*)&hbuf[CUR][hoff + 96];                          \
    if (tid < 256) {                                                         \
      xbuf[NXT][sxoff] = f2bf(xr);                                           \
      if ((S) + 2 < TSTEPS) { xr = *xnext; xnext += 2048; }                  \
    }                                                                        \
    f32x4 ac1[4], ac2[4];                                                    \
    _Pragma("unroll") for (int j = 0; j < 4; ++j) {                          \
      ac1[j] = mf(wfr[0][j], bf[0], cb[j]);                                  \
      ac2[j] = mf(wfr[3][j], bf[3], kzero);                                  \
    }                                                                        \
    _Pragma("unroll") for (int j = 0; j < 4; ++j) {                          \
      ac1[j] = mf(wfr[1][j], bf[1], ac1[j]);                                 \
      ac2[j] = mf(wfr[4][j], bf[4], ac2[j]);                                 \
    }                                                                        \
    _Pragma("unroll") for (int j = 0; j < 4; ++j) {                          \
      ac1[j] = mf(wfr[2][j], bf[2], ac1[j]);                                 \
      ac2[j] = mf(wfr[5][j], bf[5], ac2[j]);                                 \
    }                                                                        \
    float pre[4];                                                            \
    _Pragma("unroll") for (int j = 0; j < 4; ++j) {                          \
      const float u01 = m1 ? ac1[j][1] : ac1[j][0];                          \
      const float u23 = m1 ? ac1[j][3] : ac1[j][2];                          \
      const float v01 = m1 ? ac2[j][1] : ac2[j][0];                          \
      const float v23 = m1 ? ac2[j][3] : ac2[j][2];                          \
      pre[j] = (m2 ? u23 : u01) + (m2 ? v23 : v01);                          \
    }                                                                        \
    const float si = sig2(KSIG * pre[0]);                                    \
    const float sf = sig2(KSIG * pre[1]);                                    \
    const float sg = sig2(KTAN * pre[2]);                                    \
    const float so = sig2(KSIG * pre[3]);                                    \
    float cn = __builtin_fmaf(sf, cg, si);                                   \
    cn = __builtin_fmaf(-2.f, si * sg, cn);                                  \
    cg = cn;                                                                 \
    ho = so * __builtin_fmaf(-2.f, sig2(KTAN * cn), 1.f);                    \
    hbuf[NXT][hwoff] = f2bf(ho);                                             \
    *outp = ho;                                                              \
    outp += 4096;                                                            \
    sync_lds();                                                              \
  }

  for (int t = 0; t < TSTEPS; t += 2) {
    LSTM_STEP(0, 1, t);
    LSTM_STEP(1, 0, t + 1);
  }
#undef LSTM_STEP

  // ---- h_n / c_n (one float per lane) ----
  out[16777216 +         (size_t)b * 4096 + n * 128 + hgl] = ho;
  out[16777216 + 65536 + (size_t)b * 4096 + n * 128 + hgl] = cg;
}

extern "C" void kernel_launch(void* const* d_in, const int* in_sizes, int n_in,
                              void* d_out, int out_size, void* d_ws, size_t ws_size,
                              hipStream_t stream) {
  const float* x   = (const float*)d_in[0];
  const float* h0  = (const float*)d_in[1];
  const float* c0  = (const float*)d_in[2];
  const float* wih = (const float*)d_in[3];
  const float* whh = (const float*)d_in[4];
  const float* bih = (const float*)d_in[5];
  const float* bhh = (const float*)d_in[6];
  float* out = (float*)d_out;
  wide_lstm<<<128, 512, 0, stream>>>(x, h0, c0, wih, whh, bih, bhh, out);
}